// Round 2
// baseline (1446.840 us; speedup 1.0000x reference)
//
#include <hip/hip_runtime.h>
#include <math.h>

#define RNN_B 64
#define RNN_T 1024
#define RNN_D 256
#define RNN_H 256

// fast tanh: tanh(x) = sign(x) * (1 - 2t/(1+t)), t = exp(-2|x|); |err| ~1e-6
__device__ __forceinline__ float fast_tanh(float x) {
  const float ax = fabsf(x);
  const float t = __expf(-2.0f * ax);
  const float r = 1.0f - 2.0f * t / (1.0f + t);
  return copysignf(r, x);
}

// ---------------------------------------------------------------------------
// Kernel 1: xp[b,t,:] = x[b,t,:] @ Wx + b   (written into the hs region of out)
// ---------------------------------------------------------------------------
__global__ __launch_bounds__(256) void xp_gemm_kernel(
    const float* __restrict__ x, const float* __restrict__ Wx,
    const float* __restrict__ bias, float* __restrict__ xp) {
  __shared__ float xs[8][RNN_D];
  const int j = threadIdx.x;                  // output column 0..255
  const size_t row0 = (size_t)blockIdx.x * 8; // first (b*t) row

  const float4* xg = reinterpret_cast<const float4*>(x + row0 * RNN_D);
  float4* xsv = reinterpret_cast<float4*>(&xs[0][0]);
  xsv[j] = xg[j];
  xsv[j + 256] = xg[j + 256];
  __syncthreads();

  const float bj = bias[j];
  float acc[8];
#pragma unroll
  for (int r = 0; r < 8; ++r) acc[r] = bj;

  for (int k = 0; k < RNN_D; k += 4) {
    const float w0 = Wx[(size_t)(k + 0) * RNN_H + j];
    const float w1 = Wx[(size_t)(k + 1) * RNN_H + j];
    const float w2 = Wx[(size_t)(k + 2) * RNN_H + j];
    const float w3 = Wx[(size_t)(k + 3) * RNN_H + j];
#pragma unroll
    for (int r = 0; r < 8; ++r) {
      const float4 xv = *reinterpret_cast<const float4*>(&xs[r][k]);
      acc[r] = fmaf(xv.x, w0, acc[r]);
      acc[r] = fmaf(xv.y, w1, acc[r]);
      acc[r] = fmaf(xv.z, w2, acc[r]);
      acc[r] = fmaf(xv.w, w3, acc[r]);
    }
  }
#pragma unroll
  for (int r = 0; r < 8; ++r) xp[(row0 + r) * RNN_H + j] = acc[r];
}

// ---------------------------------------------------------------------------
// Kernel 2: sequential scan, one WG (512 threads = 8 waves) per batch element.
// Thread (c = tid&15, g = tid>>4): k-slice [16c,16c+16), columns [8g, 8g+8).
// Wh slice (16x8 f32) in VGPRs. Per step: 4x ds_read_b128 of h chunk (padded
// 20-float stride -> max 2-way banks), 128 FMAs, recursive-halving shuffle
// reduce (8 shfls) that both reduces over the 16 k-lanes AND lands column j
// in thread j's owner lane (j = 8g + (c>>1); lanes c and c^1 duplicate).
// xp read in place from `out`, overwritten with h_t by the same thread.
// One barrier per step; h double-buffered in 2.5 KB LDS.
// ---------------------------------------------------------------------------
__global__ __launch_bounds__(512, 2) void rnn_rec_kernel(
    const float* __restrict__ Wh, const float* __restrict__ h0,
    float* __restrict__ out, float* __restrict__ h_last) {
  const int b = blockIdx.x;
  const int tid = threadIdx.x;        // 0..511
  const int c = tid & 15;             // k-split index (16 k each)
  const int g = tid >> 4;             // column group (8 cols each)
  const bool act = (c & 1) == 0;      // final owner lanes
  const int j = 8 * g + (c >> 1);     // column this thread finalizes (if act)

  // h element k lives at float-offset (k>>4)*20 + (k&15); 80B chunk stride.
  __shared__ float hb[2][16 * 20];

  // one-time Wh slice load: wh4[i][q] = Wh[16c+i][8g+4q .. 8g+4q+3]
  float4 wh4[16][2];
#pragma unroll
  for (int i = 0; i < 16; ++i) {
    const float* wr = Wh + (size_t)(16 * c + i) * RNN_H + 8 * g;
    wh4[i][0] = *reinterpret_cast<const float4*>(wr);
    wh4[i][1] = *reinterpret_cast<const float4*>(wr + 4);
  }

  if (tid < RNN_H) hb[0][(tid >> 4) * 20 + (tid & 15)] = h0[b * RNN_H + tid];
  __syncthreads();

  float* outb = out + (size_t)b * RNN_T * RNN_H;
  float xc = act ? outb[j] : 0.0f;    // xp[b][0][j]

  int p = 0;
  for (int step = 0; step < RNN_T; ++step) {
    // prefetch next step's xp (latency hidden under FMA phase)
    float xn = 0.0f;
    if (act && step + 1 < RNN_T) xn = outb[(size_t)(step + 1) * RNN_H + j];

    // load my 16-float h chunk
    float hr[16];
    {
      const float* hp = &hb[p][c * 20];
#pragma unroll
      for (int r = 0; r < 4; ++r) {
        const float4 hv = *reinterpret_cast<const float4*>(hp + 4 * r);
        hr[4 * r + 0] = hv.x; hr[4 * r + 1] = hv.y;
        hr[4 * r + 2] = hv.z; hr[4 * r + 3] = hv.w;
      }
    }

    // 128 FMAs: 8 independent accumulator chains
    float v[8];
#pragma unroll
    for (int q = 0; q < 8; ++q) v[q] = 0.0f;
#pragma unroll
    for (int i = 0; i < 16; ++i) {
      const float hv = hr[i];
      v[0] = fmaf(hv, wh4[i][0].x, v[0]);
      v[1] = fmaf(hv, wh4[i][0].y, v[1]);
      v[2] = fmaf(hv, wh4[i][0].z, v[2]);
      v[3] = fmaf(hv, wh4[i][0].w, v[3]);
      v[4] = fmaf(hv, wh4[i][1].x, v[4]);
      v[5] = fmaf(hv, wh4[i][1].y, v[5]);
      v[6] = fmaf(hv, wh4[i][1].z, v[6]);
      v[7] = fmaf(hv, wh4[i][1].w, v[7]);
    }

    // recursive-halving reduce over the 16 c-lanes; after the s=2 stage each
    // lane holds one column's partial (jj = c>>1); final xor-1 completes it.
#pragma unroll
    for (int s = 8; s >= 2; s >>= 1) {
      const int half = s >> 1;
      const bool hi = (c & s) != 0;
#pragma unroll
      for (int q = 0; q < 8; ++q) {  // only q < half live; rest dead-coded out
        if (q < half) {
          const float keep = hi ? v[q + half] : v[q];
          const float send = hi ? v[q] : v[q + half];
          v[q] = keep + __shfl_xor(send, s);
        }
      }
    }
    v[0] += __shfl_xor(v[0], 1);

    if (act) {
      const float h = fast_tanh(v[0] + xc);
      hb[p ^ 1][(j >> 4) * 20 + (j & 15)] = h;
      outb[(size_t)step * RNN_H + j] = h;
      if (step == RNN_T - 1) h_last[b * RNN_H + j] = h;
    }
    __syncthreads();
    p ^= 1;
    xc = xn;
  }
}

extern "C" void kernel_launch(void* const* d_in, const int* in_sizes, int n_in,
                              void* d_out, int out_size, void* d_ws, size_t ws_size,
                              hipStream_t stream) {
  const float* x    = (const float*)d_in[0];
  const float* h0   = (const float*)d_in[1];
  const float* Wx   = (const float*)d_in[2];
  const float* Wh   = (const float*)d_in[3];
  const float* bias = (const float*)d_in[4];
  float* out = (float*)d_out;
  float* h_last = out + (size_t)RNN_B * RNN_T * RNN_H;

  xp_gemm_kernel<<<RNN_B * RNN_T / 8, 256, 0, stream>>>(x, Wx, bias, out);
  rnn_rec_kernel<<<RNN_B, 512, 0, stream>>>(Wh, h0, out, h_last);
}

// Round 3
// 1247.350 us; speedup vs baseline: 1.1599x; 1.1599x over previous
//
#include <hip/hip_runtime.h>

#define RNN_B 64
#define RNN_T 1024
#define RNN_D 256
#define RNN_H 256

typedef __attribute__((ext_vector_type(8))) short bf16x8;
typedef __attribute__((ext_vector_type(4))) float f32x4;

__device__ __forceinline__ unsigned short f32_to_bf16_rne(float f) {
  unsigned u = __builtin_bit_cast(unsigned, f);
  u += 0x7fffu + ((u >> 16) & 1u);
  return (unsigned short)(u >> 16);
}

// branch-free tanh: 1 - 2/(exp(2x)+1); exact at +/-inf, ~1e-6 abs err
__device__ __forceinline__ float tanh_fast(float x) {
  const float t = __expf(2.0f * x);
  const float r = __builtin_amdgcn_rcpf(t + 1.0f);
  return fmaf(-2.0f, r, 1.0f);
}

// swizzled u16 index of h[batch][col] in an 8KB LDS buffer.
// XOR of (batch&7)<<4 on the byte offset spreads the 16 batch rows across
// 8 distinct 16B bank-slots -> ds_read_b128 of A-frags is conflict-free.
__device__ __forceinline__ int hidx(int batch, int col) {
  return (batch * 512 + ((col * 2) ^ ((batch & 7) << 4))) >> 1;
}

__device__ __forceinline__ void wg_barrier_lds_only() {
  // drain LDS ops only; deliberately NOT vmcnt -> global xp prefetch and h
  // stores stay in flight across steps (avoids __syncthreads' vmcnt(0) drain)
  asm volatile("s_waitcnt lgkmcnt(0)" ::: "memory");
  __builtin_amdgcn_sched_barrier(0);
  __builtin_amdgcn_s_barrier();
  __builtin_amdgcn_sched_barrier(0);
}

// ---------------------------------------------------------------------------
// Kernel 1: xp[b,t,:] = x[b,t,:] @ Wx + b  (into the hs region of out) — f32
// ---------------------------------------------------------------------------
__global__ __launch_bounds__(256) void xp_gemm_kernel(
    const float* __restrict__ x, const float* __restrict__ Wx,
    const float* __restrict__ bias, float* __restrict__ xp) {
  __shared__ float xs[8][RNN_D];
  const int j = threadIdx.x;
  const size_t row0 = (size_t)blockIdx.x * 8;

  const float4* xg = reinterpret_cast<const float4*>(x + row0 * RNN_D);
  float4* xsv = reinterpret_cast<float4*>(&xs[0][0]);
  xsv[j] = xg[j];
  xsv[j + 256] = xg[j + 256];
  __syncthreads();

  const float bj = bias[j];
  float acc[8];
#pragma unroll
  for (int r = 0; r < 8; ++r) acc[r] = bj;

  for (int k = 0; k < RNN_D; k += 4) {
    const float w0 = Wx[(size_t)(k + 0) * RNN_H + j];
    const float w1 = Wx[(size_t)(k + 1) * RNN_H + j];
    const float w2 = Wx[(size_t)(k + 2) * RNN_H + j];
    const float w3 = Wx[(size_t)(k + 3) * RNN_H + j];
#pragma unroll
    for (int r = 0; r < 8; ++r) {
      const float4 xv = *reinterpret_cast<const float4*>(&xs[r][k]);
      acc[r] = fmaf(xv.x, w0, acc[r]);
      acc[r] = fmaf(xv.y, w1, acc[r]);
      acc[r] = fmaf(xv.z, w2, acc[r]);
      acc[r] = fmaf(xv.w, w3, acc[r]);
    }
  }
#pragma unroll
  for (int r = 0; r < 8; ++r) xp[(row0 + r) * RNN_H + j] = acc[r];
}

// ---------------------------------------------------------------------------
// One recurrence step (RD = LDS read-buffer, TOFF = 0/1 within unroll pair).
// Lane roles (per wave, tiles nt = wid*4+i):
//   A-frag (h):  row(batch) = lane&15, k = kc*32 + (lane>>4)*8 + j
//   B-frag (Wh): col = 16*nt + (lane&15), k same — held in VGPRs
//   C/xp/out:    col = 16*nt + (lane&15), batch = (lane>>4)*4 + reg
// acc is initialized with xp (C-in) -> no separate add, no reduction.
// ---------------------------------------------------------------------------
template <int RD, int TOFF>
__device__ __forceinline__ void rnn_step(
    unsigned short (&hb)[2][16 * 256], const bf16x8 (&bfrag)[4][8],
    float (&xc)[4][4], float (&xn)[4][4],
    const float* const (&xp_ld)[4], float* const (&h_st)[4],
    float* const (&hl_st)[4], bool last, int lrow, int lq, int col0) {
  // 1) prefetch xp for the NEXT step (consumed after the next barrier)
#pragma unroll
  for (int r = 0; r < 4; ++r)
#pragma unroll
    for (int i = 0; i < 4; ++i)
      xn[i][r] = xp_ld[r][TOFF * RNN_H + i * 16];

  // 2) A-fragments of h from LDS (8 x ds_read_b128, swizzled)
  bf16x8 af[8];
#pragma unroll
  for (int kc = 0; kc < 8; ++kc) {
    const int off = (lrow * 512 + ((kc * 64 + lq * 16) ^ ((lrow & 7) << 4))) >> 1;
    af[kc] = *reinterpret_cast<const bf16x8*>(&hb[RD][off]);
  }

  // 3) MFMA chain, acc seeded with xp
  f32x4 acc[4];
#pragma unroll
  for (int i = 0; i < 4; ++i) {
    f32x4 a = {xc[i][0], xc[i][1], xc[i][2], xc[i][3]};
    acc[i] = a;
  }
#pragma unroll
  for (int kc = 0; kc < 8; ++kc)
#pragma unroll
    for (int i = 0; i < 4; ++i)
      acc[i] = __builtin_amdgcn_mfma_f32_16x16x32_bf16(af[kc], bfrag[i][kc],
                                                       acc[i], 0, 0, 0);

  // 4) tanh, store f32 h to out (no drain), bf16 h -> other LDS buffer
#pragma unroll
  for (int i = 0; i < 4; ++i) {
#pragma unroll
    for (int r = 0; r < 4; ++r) {
      const float h = tanh_fast(acc[i][r]);
      h_st[r][TOFF * RNN_H + i * 16] = h;
      if (last) hl_st[r][i * 16] = h;
      hb[RD ^ 1][hidx(lq * 4 + r, col0 + i * 16)] = f32_to_bf16_rne(h);
    }
  }

  // 5) LDS-only barrier (global ops remain in flight)
  wg_barrier_lds_only();
}

// ---------------------------------------------------------------------------
// Kernel 2: MFMA recurrence. 4 WGs x 16 batches, 4 waves (256 thr) each.
// ---------------------------------------------------------------------------
__global__ __launch_bounds__(256, 1) void rnn_rec_mfma(
    const float* __restrict__ Wh, const float* __restrict__ h0, float* out,
    float* h_last) {
  __shared__ unsigned short hb[2][16 * 256];

  const int bg = blockIdx.x;
  const int tid = threadIdx.x;
  const int wid = tid >> 6;
  const int lane = tid & 63;
  const int lrow = lane & 15;
  const int lq = lane >> 4;
  const int col0 = wid * 64 + lrow;

  // ---- one-time: Wh B-fragments (f32 -> bf16, RNE) into VGPRs ----------
  bf16x8 bfrag[4][8];
#pragma unroll
  for (int i = 0; i < 4; ++i) {
    const int col = (wid * 4 + i) * 16 + lrow;
#pragma unroll
    for (int kc = 0; kc < 8; ++kc) {
      bf16x8 v;
#pragma unroll
      for (int j = 0; j < 8; ++j) {
        const int k = kc * 32 + lq * 8 + j;
        v[j] = (short)f32_to_bf16_rne(Wh[(size_t)k * RNN_H + col]);
      }
      bfrag[i][kc] = v;
    }
  }

  // ---- one-time: h0 -> hb[0] (bf16, swizzled) --------------------------
  {
    const int b = tid >> 4;
    const int c0 = (tid & 15) * 16;
#pragma unroll
    for (int c = 0; c < 16; ++c) {
      const float v = h0[(size_t)(bg * 16 + b) * RNN_H + c0 + c];
      hb[0][hidx(b, c0 + c)] = f32_to_bf16_rne(v);
    }
  }

  // per-lane global base pointers (one per batch r of my quad)
  float* outb = out + (size_t)bg * 16 * RNN_T * RNN_H;
  float* hbase[4];
  const float* xp_ld[4];
  float* h_st[4];
  float* hl_st[4];
#pragma unroll
  for (int r = 0; r < 4; ++r) {
    hbase[r] = outb + (size_t)(lq * 4 + r) * RNN_T * RNN_H + col0;
    xp_ld[r] = hbase[r] + RNN_H;  // -> xp[t=1]
    h_st[r] = hbase[r];           // -> h[t=0]
    hl_st[r] = h_last + (size_t)(bg * 16 + lq * 4 + r) * RNN_H + col0;
  }

  // prologue: xp[t=0] into xA
  float xA[4][4], xB[4][4];
#pragma unroll
  for (int r = 0; r < 4; ++r)
#pragma unroll
    for (int i = 0; i < 4; ++i) xA[i][r] = hbase[r][i * 16];

  wg_barrier_lds_only();  // h0 staging visible

#pragma unroll 1
  for (int t = 0; t < RNN_T; t += 2) {
    const bool lastp = (t == RNN_T - 2);
    rnn_step<0, 0>(hb, bfrag, xA, xB, xp_ld, h_st, hl_st, false, lrow, lq, col0);
    rnn_step<1, 1>(hb, bfrag, xB, xA, xp_ld, h_st, hl_st, lastp, lrow, lq, col0);
#pragma unroll
    for (int r = 0; r < 4; ++r) {
      xp_ld[r] += 2 * RNN_H;
      h_st[r] += 2 * RNN_H;
    }
  }
}

extern "C" void kernel_launch(void* const* d_in, const int* in_sizes, int n_in,
                              void* d_out, int out_size, void* d_ws, size_t ws_size,
                              hipStream_t stream) {
  const float* x = (const float*)d_in[0];
  const float* h0 = (const float*)d_in[1];
  const float* Wx = (const float*)d_in[2];
  const float* Wh = (const float*)d_in[3];
  const float* bias = (const float*)d_in[4];
  float* out = (float*)d_out;
  float* h_last = out + (size_t)RNN_B * RNN_T * RNN_H;

  xp_gemm_kernel<<<RNN_B * RNN_T / 8, 256, 0, stream>>>(x, Wx, bias, out);
  rnn_rec_mfma<<<RNN_B / 16, 256, 0, stream>>>(Wh, h0, out, h_last);
}

// Round 4
// 1071.332 us; speedup vs baseline: 1.3505x; 1.1643x over previous
//
#include <hip/hip_runtime.h>

#define RNN_B 64
#define RNN_T 1024
#define RNN_D 256
#define RNN_H 256

typedef __attribute__((ext_vector_type(8))) short bf16x8;
typedef __attribute__((ext_vector_type(4))) float f32x4;

__device__ __forceinline__ unsigned short f32_to_bf16_rne(float f) {
  unsigned u = __builtin_bit_cast(unsigned, f);
  u += 0x7fffu + ((u >> 16) & 1u);
  return (unsigned short)(u >> 16);
}

// branch-free tanh: 1 - 2/(exp(2x)+1); exact at +/-inf, ~1e-6 abs err
__device__ __forceinline__ float tanh_fast(float x) {
  const float t = __expf(2.0f * x);
  const float r = __builtin_amdgcn_rcpf(t + 1.0f);
  return fmaf(-2.0f, r, 1.0f);
}

// swizzled u16 index of h[batch][col] in an 8KB LDS buffer.
// XOR of (batch&7)<<4 on the byte offset spreads the 16 batch rows across
// 8 distinct 16B bank-slots -> ds_read_b128 of A-frags is conflict-free.
__device__ __forceinline__ int hidx(int batch, int col) {
  return (batch * 512 + ((col * 2) ^ ((batch & 7) << 4))) >> 1;
}

__device__ __forceinline__ void wg_barrier_lds_only() {
  // drain LDS ops only; deliberately NOT vmcnt -> global xp prefetch and h
  // stores stay in flight across steps (avoids __syncthreads' vmcnt(0) drain)
  asm volatile("s_waitcnt lgkmcnt(0)" ::: "memory");
  __builtin_amdgcn_sched_barrier(0);
  __builtin_amdgcn_s_barrier();
  __builtin_amdgcn_sched_barrier(0);
}

// ---------------------------------------------------------------------------
// Kernel 1: xp[b,t,:] = x[b,t,:] @ Wx + b  (into the hs region of out) — f32
// ---------------------------------------------------------------------------
__global__ __launch_bounds__(256) void xp_gemm_kernel(
    const float* __restrict__ x, const float* __restrict__ Wx,
    const float* __restrict__ bias, float* __restrict__ xp) {
  __shared__ float xs[8][RNN_D];
  const int j = threadIdx.x;
  const size_t row0 = (size_t)blockIdx.x * 8;

  const float4* xg = reinterpret_cast<const float4*>(x + row0 * RNN_D);
  float4* xsv = reinterpret_cast<float4*>(&xs[0][0]);
  xsv[j] = xg[j];
  xsv[j + 256] = xg[j + 256];
  __syncthreads();

  const float bj = bias[j];
  float acc[8];
#pragma unroll
  for (int r = 0; r < 8; ++r) acc[r] = bj;

  for (int k = 0; k < RNN_D; k += 4) {
    const float w0 = Wx[(size_t)(k + 0) * RNN_H + j];
    const float w1 = Wx[(size_t)(k + 1) * RNN_H + j];
    const float w2 = Wx[(size_t)(k + 2) * RNN_H + j];
    const float w3 = Wx[(size_t)(k + 3) * RNN_H + j];
#pragma unroll
    for (int r = 0; r < 8; ++r) {
      const float4 xv = *reinterpret_cast<const float4*>(&xs[r][k]);
      acc[r] = fmaf(xv.x, w0, acc[r]);
      acc[r] = fmaf(xv.y, w1, acc[r]);
      acc[r] = fmaf(xv.z, w2, acc[r]);
      acc[r] = fmaf(xv.w, w3, acc[r]);
    }
  }
#pragma unroll
  for (int r = 0; r < 8; ++r) xp[(row0 + r) * RNN_H + j] = acc[r];
}

// ---------------------------------------------------------------------------
// One recurrence step (RD = LDS read-buffer, TOFF = 0/1 within unroll pair).
// 8 waves; wave wid owns col-tiles nt = 2*wid + i (i in {0,1}) = 32 columns.
// Lane roles per tile:
//   A-frag (h):  row(batch) = lane&15, k = kc*32 + (lane>>4)*8 + j
//   B-frag (Wh): col = 16*nt + (lane&15), k same — held in VGPRs
//   C/xp/out:    col = 16*nt + (lane&15), batch = (lane>>4)*4 + reg
// acc seeded with xp (C-in) -> no separate add, no reduction.
// ---------------------------------------------------------------------------
template <int RD, int TOFF>
__device__ __forceinline__ void rnn_step(
    unsigned short (&hb)[2][16 * 256], const bf16x8 (&bfrag)[2][8],
    float (&xc)[2][4], float (&xn)[2][4],
    const float* const (&xp_ld)[4], float* const (&h_st)[4],
    float* const (&hl_st)[4], bool last, int lrow, int lq, int col0) {
  // 1) prefetch xp for the NEXT step (consumed after the next barrier)
#pragma unroll
  for (int r = 0; r < 4; ++r)
#pragma unroll
    for (int i = 0; i < 2; ++i)
      xn[i][r] = xp_ld[r][TOFF * RNN_H + i * 16];

  // 2) A-fragments of h from LDS (8 x ds_read_b128, swizzled)
  bf16x8 af[8];
#pragma unroll
  for (int kc = 0; kc < 8; ++kc) {
    const int off = (lrow * 512 + ((kc * 64 + lq * 16) ^ ((lrow & 7) << 4))) >> 1;
    af[kc] = *reinterpret_cast<const bf16x8*>(&hb[RD][off]);
  }

  // 3) MFMA chain, acc seeded with xp
  f32x4 acc[2];
#pragma unroll
  for (int i = 0; i < 2; ++i) {
    f32x4 a = {xc[i][0], xc[i][1], xc[i][2], xc[i][3]};
    acc[i] = a;
  }
  __builtin_amdgcn_s_setprio(1);
#pragma unroll
  for (int kc = 0; kc < 8; ++kc)
#pragma unroll
    for (int i = 0; i < 2; ++i)
      acc[i] = __builtin_amdgcn_mfma_f32_16x16x32_bf16(af[kc], bfrag[i][kc],
                                                       acc[i], 0, 0, 0);
  __builtin_amdgcn_s_setprio(0);

  // 4) tanh, store f32 h to out (no drain), bf16 h -> other LDS buffer
#pragma unroll
  for (int i = 0; i < 2; ++i) {
#pragma unroll
    for (int r = 0; r < 4; ++r) {
      const float h = tanh_fast(acc[i][r]);
      h_st[r][TOFF * RNN_H + i * 16] = h;
      if (last) hl_st[r][i * 16] = h;
      hb[RD ^ 1][hidx(lq * 4 + r, col0 + i * 16)] = f32_to_bf16_rne(h);
    }
  }

  // 5) LDS-only barrier (global ops remain in flight)
  wg_barrier_lds_only();
}

// ---------------------------------------------------------------------------
// Kernel 2: MFMA recurrence. 4 WGs x 16 batches, 8 waves (512 thr) each
// -> 2 waves/SIMD so LDS/MFMA/trans latency cross-hides.
// ---------------------------------------------------------------------------
__global__ __launch_bounds__(512, 2) void rnn_rec_mfma(
    const float* __restrict__ Wh, const float* __restrict__ h0, float* out,
    float* h_last) {
  __shared__ unsigned short hb[2][16 * 256];

  const int bg = blockIdx.x;
  const int tid = threadIdx.x;
  const int wid = tid >> 6;      // 0..7
  const int lane = tid & 63;
  const int lrow = lane & 15;
  const int lq = lane >> 4;
  const int col0 = wid * 32 + lrow;

  // ---- one-time: Wh B-fragments (f32 -> bf16, RNE) into VGPRs ----------
  bf16x8 bfrag[2][8];
#pragma unroll
  for (int i = 0; i < 2; ++i) {
    const int col = (wid * 2 + i) * 16 + lrow;
#pragma unroll
    for (int kc = 0; kc < 8; ++kc) {
      bf16x8 v;
#pragma unroll
      for (int j = 0; j < 8; ++j) {
        const int k = kc * 32 + lq * 8 + j;
        v[j] = (short)f32_to_bf16_rne(Wh[(size_t)k * RNN_H + col]);
      }
      bfrag[i][kc] = v;
    }
  }

  // ---- one-time: h0 -> hb[0] (bf16, swizzled) --------------------------
  {
    const int b = tid >> 5;            // 0..15
    const int c0 = (tid & 31) * 8;     // 8 cols per thread
#pragma unroll
    for (int c = 0; c < 8; ++c) {
      const float v = h0[(size_t)(bg * 16 + b) * RNN_H + c0 + c];
      hb[0][hidx(b, c0 + c)] = f32_to_bf16_rne(v);
    }
  }

  // per-lane global base pointers (one per batch r of my quad)
  float* outb = out + (size_t)bg * 16 * RNN_T * RNN_H;
  float* hbase[4];
  const float* xp_ld[4];
  float* h_st[4];
  float* hl_st[4];
#pragma unroll
  for (int r = 0; r < 4; ++r) {
    hbase[r] = outb + (size_t)(lq * 4 + r) * RNN_T * RNN_H + col0;
    xp_ld[r] = hbase[r] + RNN_H;  // -> xp[t=1]
    h_st[r] = hbase[r];           // -> h[t=0]
    hl_st[r] = h_last + (size_t)(bg * 16 + lq * 4 + r) * RNN_H + col0;
  }

  // prologue: xp[t=0] into xA
  float xA[2][4], xB[2][4];
#pragma unroll
  for (int r = 0; r < 4; ++r)
#pragma unroll
    for (int i = 0; i < 2; ++i) xA[i][r] = hbase[r][i * 16];

  wg_barrier_lds_only();  // h0 staging visible

#pragma unroll 1
  for (int t = 0; t < RNN_T; t += 2) {
    const bool lastp = (t == RNN_T - 2);
    rnn_step<0, 0>(hb, bfrag, xA, xB, xp_ld, h_st, hl_st, false, lrow, lq, col0);
    rnn_step<1, 1>(hb, bfrag, xB, xA, xp_ld, h_st, hl_st, lastp, lrow, lq, col0);
#pragma unroll
    for (int r = 0; r < 4; ++r) {
      xp_ld[r] += 2 * RNN_H;
      h_st[r] += 2 * RNN_H;
    }
  }
}

extern "C" void kernel_launch(void* const* d_in, const int* in_sizes, int n_in,
                              void* d_out, int out_size, void* d_ws, size_t ws_size,
                              hipStream_t stream) {
  const float* x = (const float*)d_in[0];
  const float* h0 = (const float*)d_in[1];
  const float* Wx = (const float*)d_in[2];
  const float* Wh = (const float*)d_in[3];
  const float* bias = (const float*)d_in[4];
  float* out = (float*)d_out;
  float* h_last = out + (size_t)RNN_B * RNN_T * RNN_H;

  xp_gemm_kernel<<<RNN_B * RNN_T / 8, 256, 0, stream>>>(x, Wx, bias, out);
  rnn_rec_mfma<<<RNN_B / 16, 512, 0, stream>>>(Wh, h0, out, h_last);
}